// Round 8
// baseline (295.413 us; speedup 1.0000x reference)
//
#include <hip/hip_runtime.h>
#include <cmath>

#define T_DIM 2048
#define B_DIM 8
#define C_DIM 1024
#define H_DIM 8
#define R_DIM 128
#define BH_DIM 64          // B*H
#define COLS 8192          // BH*R
#define COL4 2048          // COLS/4
#define NCH 64             // scan chunks
#define LT 32              // T per chunk
__device__ __constant__ float INV_K = 0.33333333333333333f;

typedef _Float16 h4 __attribute__((ext_vector_type(4)));
typedef _Float16 h8 __attribute__((ext_vector_type(8)));

// ---- Fused single-pass: offsets GEMM + chunk sums + chained-scan + fp16 S ----
// Grid 512 = 8 col-groups (cg == batch b) x 64 chunks. Chunk identity comes
// from an atomicAdd ticket (arrival order) -> predecessors of any spinning
// block are already resident -> deadlock-free without cooperative launch.
// x[chunk rows] held in v[32] registers: read ONCE, used for GEMM partials,
// chunk sums, and the final scan. Publish: csum + threadfence + release flag;
// wait: one ballot'd 64-flag vector load per spin iteration.
__global__ __launch_bounds__(256, 2) void fused_scan_kernel(
        const float4* __restrict__ x4, const float* __restrict__ W,
        const float* __restrict__ bias, _Float16* __restrict__ S,
        float* __restrict__ off, float4* __restrict__ csum4,
        int* __restrict__ tickets, int* __restrict__ flags) {
    __shared__ float Wt[16 * 1024];          // 64 KB
    __shared__ float sdata[4][8][64];        // 8 KB
    __shared__ int s_vch;
    const int cg = blockIdx.x >> 6;          // 0..7 == batch index b
    const int tid = threadIdx.x;
    const int wave = tid >> 6, lane = tid & 63;

    if (tid == 0) s_vch = atomicAdd(&tickets[cg], 1);   // device-scope
    __syncthreads();
    const int vch = s_vch;                   // this block's chunk in [0,64)
    const int col4 = cg * 256 + tid;         // global col4 in [0, 2048)

    // ---- single x read: all 32 rows of this chunk into registers ----
    const float4* xp = x4 + (size_t)(vch * LT) * COL4 + col4;
    float4 v[32];
#pragma unroll
    for (int t = 0; t < LT; ++t) v[t] = xp[(size_t)t * COL4];

    // ---- stage Wt[j][c] (transposed) ----
    for (int idx = tid; idx < 4096; idx += 256) {
        int c = idx >> 2, j4 = (idx & 3) * 4;
        float4 w = *reinterpret_cast<const float4*>(W + c * 16 + j4);
        Wt[(j4 + 0) * 1024 + c] = w.x;
        Wt[(j4 + 1) * 1024 + c] = w.y;
        Wt[(j4 + 2) * 1024 + c] = w.z;
        Wt[(j4 + 3) * 1024 + c] = w.w;
    }
    __syncthreads();

    // ---- offsets GEMM partials (proven round-6 body) ----
    const int cbase = tid * 4;
#pragma unroll 1
    for (int g = 0; g < 8; ++g) {
        float acc[64];
#pragma unroll
        for (int i = 0; i < 64; ++i) acc[i] = 0.f;
#pragma unroll
        for (int j = 0; j < 16; ++j) {
            float4 w = *reinterpret_cast<const float4*>(&Wt[j * 1024 + cbase]);
            float4 c0 = v[g * 4 + 0], c1 = v[g * 4 + 1];
            float4 c2 = v[g * 4 + 2], c3 = v[g * 4 + 3];
            acc[j]      = fmaf(c0.x, w.x, fmaf(c0.y, w.y, fmaf(c0.z, w.z, fmaf(c0.w, w.w, acc[j]))));
            acc[16 + j] = fmaf(c1.x, w.x, fmaf(c1.y, w.y, fmaf(c1.z, w.z, fmaf(c1.w, w.w, acc[16 + j]))));
            acc[32 + j] = fmaf(c2.x, w.x, fmaf(c2.y, w.y, fmaf(c2.z, w.z, fmaf(c2.w, w.w, acc[32 + j]))));
            acc[48 + j] = fmaf(c3.x, w.x, fmaf(c3.y, w.y, fmaf(c3.z, w.z, fmaf(c3.w, w.w, acc[48 + j]))));
        }
        // value-folding wave reduction: lane l ends with value (tl<<4)|j
#pragma unroll
        for (int m = 32; m >= 1; m >>= 1) {
            bool hi = (lane & m) != 0;
#pragma unroll
            for (int i = 0; i < m; ++i) {
                float send = hi ? acc[i] : acc[i + m];
                float recv = __shfl_xor(send, m, 64);
                acc[i] = (hi ? acc[i + m] : acc[i]) + recv;
            }
        }
        sdata[wave][g][lane] = acc[0];
    }

    // ---- chunk aggregate -> csum, publish with release flag ----
    float csx = 0.f, csy = 0.f, csz = 0.f, csw = 0.f;
#pragma unroll
    for (int t = 0; t < LT; ++t) {
        csx += v[t].x; csy += v[t].y; csz += v[t].z; csw += v[t].w;
    }
    float4 agg; agg.x = csx * INV_K; agg.y = csy * INV_K; agg.z = csz * INV_K; agg.w = csw * INV_K;
    csum4[(size_t)vch * COL4 + col4] = agg;
    __threadfence();                          // flush own store to agent scope
    __syncthreads();                          // all csum stores + sdata done
    if (tid == 0)
        __hip_atomic_store(&flags[cg * 64 + vch], 1,
                           __ATOMIC_RELEASE, __HIP_MEMORY_SCOPE_AGENT);

    // ---- off write (independent of prefix; overlaps the spin below) ----
#pragma unroll
    for (int i = 0; i < 2; ++i) {
        int idx = tid + i * 256;
        int g = idx >> 6, l = idx & 63;
        int tl = l >> 4, j = l & 15;
        float s = sdata[0][g][l] + sdata[1][g][l] + sdata[2][g][l] + sdata[3][g][l];
        s += bias[j];
        int t = vch * LT + g * 4 + tl;
        off[((size_t)t * B_DIM + cg) * 16 + j] = 1.f / (1.f + expf(-s));
    }

    // ---- wait for predecessors: one 64-flag vector load per iteration ----
    if (vch > 0) {
        const int* fbase = flags + cg * 64;
        while (true) {
            int f = (lane < vch)
                ? __hip_atomic_load(&fbase[lane], __ATOMIC_ACQUIRE, __HIP_MEMORY_SCOPE_AGENT)
                : 1;
            if (__all(f != 0)) break;
            __builtin_amdgcn_s_sleep(2);
        }
    }
    __threadfence();                          // acquire: invalidate stale lines

    // ---- prefix over predecessors + in-register scan -> fp16 S ----
    float rx = 0.f, ry = 0.f, rz = 0.f, rw = 0.f;
    for (int c = 0; c < vch; ++c) {
        float4 p = csum4[(size_t)c * COL4 + col4];
        rx += p.x; ry += p.y; rz += p.z; rw += p.w;
    }
    _Float16* Sp = S + (size_t)(vch * LT) * COLS + col4 * 4;
#pragma unroll
    for (int t = 0; t < LT; ++t) {
        rx = fmaf(v[t].x, INV_K, rx);
        ry = fmaf(v[t].y, INV_K, ry);
        rz = fmaf(v[t].z, INV_K, rz);
        rw = fmaf(v[t].w, INV_K, rw);
        h4 o; o.x = (_Float16)rx; o.y = (_Float16)ry; o.z = (_Float16)rz; o.w = (_Float16)rw;
        *reinterpret_cast<h4*>(Sp + (size_t)t * COLS) = o;
    }
}

// ---- Gather (round-6 proven): fp16 S, 8 out/thread, bijective XCD swizzle ----
__global__ void gather_kernel(const _Float16* __restrict__ S, const float* __restrict__ off,
                              float* __restrict__ out) {
    int bid = blockIdx.x;
    int sbid = (bid & 7) * 1024 + (bid >> 3);   // 8192 % 8 == 0 -> bijective
    int vid = sbid * 256 + threadIdx.x;         // T*B*C/8 vec elements
    int r8 = (vid & 15) << 3;
    int bh = (vid >> 4) & 63;
    int t = vid >> 10;
    int b = bh >> 3, h = bh & 7;
    const float* o = off + ((size_t)t * B_DIM + b) * 16;
    float aL = o[h], aR = o[8 + h];
    float tf = (float)t;
    float lenL = 1.f + aL * fmaxf(tf - 1.f, 0.f);
    float lenR = 1.f + aR * fmaxf((float)(T_DIM - 1) - tf - 1.f, 0.f);
    float fL = fmaxf(tf - lenL - 1.f, -1.f);
    float fR = fminf(tf + lenR, (float)(T_DIM - 1));
    int col = (bh << 7) | r8;

    float ffL = floorf(fL); int i0L = (int)ffL; float frL = fL - ffL;
    float ffR = floorf(fR); int i0R = (int)ffR; float frR = fR - ffR;
    int i0Lc = min(max(i0L, 0), T_DIM - 1), i1Lc = min(i0L + 1, T_DIM - 1);
    int i0Rc = min(max(i0R, 0), T_DIM - 1), i1Rc = min(i0R + 1, T_DIM - 1);

    const h8 zero8 = {0, 0, 0, 0, 0, 0, 0, 0};
    h8 v1L = *reinterpret_cast<const h8*>(S + (size_t)i1Lc * COLS + col);
    h8 v0L = (i0L >= 0) ? *reinterpret_cast<const h8*>(S + (size_t)i0Lc * COLS + col) : zero8;
    h8 v1R = *reinterpret_cast<const h8*>(S + (size_t)i1Rc * COLS + col);
    h8 v0R = (i0R >= 0) ? *reinterpret_cast<const h8*>(S + (size_t)i0Rc * COLS + col) : zero8;

    float res[8];
#pragma unroll
    for (int i = 0; i < 8; ++i) {
        float a0 = (float)v0R[i], a1 = (float)v1R[i];
        float b0 = (float)v0L[i], b1 = (float)v1L[i];
        res[i] = fmaf(frR, a1 - a0, a0) - fmaf(frL, b1 - b0, b0);
    }
    float* op = out + (size_t)vid * 8;
    *reinterpret_cast<float4*>(op)     = make_float4(res[0], res[1], res[2], res[3]);
    *reinterpret_cast<float4*>(op + 4) = make_float4(res[4], res[5], res[6], res[7]);
}

extern "C" void kernel_launch(void* const* d_in, const int* in_sizes, int n_in,
                              void* d_out, int out_size, void* d_ws, size_t ws_size,
                              hipStream_t stream) {
    const float4* x4 = (const float4*)d_in[0];
    const float* W  = (const float*)d_in[1];
    const float* bi = (const float*)d_in[2];

    char* ws = (char*)d_ws;
    const size_t S_bytes    = (size_t)T_DIM * COLS * sizeof(_Float16);    // 32 MB
    const size_t off_bytes  = (size_t)T_DIM * B_DIM * 16 * sizeof(float); // 1 MB
    const size_t csum_bytes = (size_t)NCH * COL4 * sizeof(float4);        // 2 MB
    _Float16* S  = (_Float16*)ws;
    float* off   = (float*)(ws + S_bytes);
    float* csum  = (float*)(ws + S_bytes + off_bytes);
    int* tickets = (int*)(ws + S_bytes + off_bytes + csum_bytes);         // 8 ints
    int* flags   = tickets + 8;                                           // 512 ints

    hipMemsetAsync(tickets, 0, (8 + 8 * 64) * sizeof(int), stream);
    fused_scan_kernel<<<512, 256, 0, stream>>>(x4, W, bi, S, off,
                                               (float4*)csum, tickets, flags);
    gather_kernel<<<(T_DIM * B_DIM * C_DIM / 8) / 256, 256, 0, stream>>>(
        S, off, (float*)d_out);
}

// Round 9
// 76.766 us; speedup vs baseline: 3.8482x; 3.8482x over previous
//
#include <hip/hip_runtime.h>
#include <cmath>

#define T_DIM 2048
#define B_DIM 8
#define C_DIM 1024
#define H_DIM 8
#define R_DIM 128
#define BH_DIM 64          // B*H
#define COLS 8192          // BH*R
#define COL4 2048          // COLS/4
#define NCH 64             // scan chunks
#define LT 32              // T per chunk
__device__ __constant__ float INV_K = 0.33333333333333333f;

typedef _Float16 h4 __attribute__((ext_vector_type(4)));
typedef _Float16 h8 __attribute__((ext_vector_type(8)));

// ---- Kernel A: offsets GEMM + chunk sums + LOCAL scan (ONE x read) ----
// Round-6 proven streaming body (c0..c3 scalars, NO register array -> no
// rule-#20 scratch spill). Adds: running local scan rx..rw over the chunk,
// stored to Sloc as fp16. No inter-block dependency (prefix added later).
__global__ __launch_bounds__(256, 2) void offcsum_kernel(
        const float4* __restrict__ x4, const float* __restrict__ W,
        const float* __restrict__ bias, float* __restrict__ off,
        float4* __restrict__ csum4, _Float16* __restrict__ Sloc) {
    __shared__ float Wt[16 * 1024];          // 64 KB
    __shared__ float sdata[4][8][64];        // 8 KB
    const int bid = blockIdx.x;
    const int cg = bid >> 6;                 // 0..7  == batch index b
    const int ch = bid & 63;                 // 0..63 == t chunk
    const int tid = threadIdx.x;
    const int wave = tid >> 6, lane = tid & 63;
    const int col4 = cg * 256 + tid;         // global col4 in [0, 2048)

    for (int idx = tid; idx < 4096; idx += 256) {
        int c = idx >> 2, j4 = (idx & 3) * 4;
        float4 w = *reinterpret_cast<const float4*>(W + c * 16 + j4);
        Wt[(j4 + 0) * 1024 + c] = w.x;
        Wt[(j4 + 1) * 1024 + c] = w.y;
        Wt[(j4 + 2) * 1024 + c] = w.z;
        Wt[(j4 + 3) * 1024 + c] = w.w;
    }
    __syncthreads();

    const float4* xp = x4 + (size_t)(ch * LT) * COL4 + col4;
    _Float16* Sp = Sloc + (size_t)(ch * LT) * COLS + col4 * 4;
    const int cbase = tid * 4;
    float csx = 0.f, csy = 0.f, csz = 0.f, csw = 0.f;   // chunk sum
    float rx = 0.f, ry = 0.f, rz = 0.f, rw = 0.f;       // local running scan

#pragma unroll 1
    for (int g = 0; g < 8; ++g) {
        float4 c0 = xp[(size_t)(g * 4 + 0) * COL4];
        float4 c1 = xp[(size_t)(g * 4 + 1) * COL4];
        float4 c2 = xp[(size_t)(g * 4 + 2) * COL4];
        float4 c3 = xp[(size_t)(g * 4 + 3) * COL4];
        float acc[64];
#pragma unroll
        for (int i = 0; i < 64; ++i) acc[i] = 0.f;
#pragma unroll
        for (int j = 0; j < 16; ++j) {
            float4 w = *reinterpret_cast<const float4*>(&Wt[j * 1024 + cbase]);
            acc[j]      = fmaf(c0.x, w.x, fmaf(c0.y, w.y, fmaf(c0.z, w.z, fmaf(c0.w, w.w, acc[j]))));
            acc[16 + j] = fmaf(c1.x, w.x, fmaf(c1.y, w.y, fmaf(c1.z, w.z, fmaf(c1.w, w.w, acc[16 + j]))));
            acc[32 + j] = fmaf(c2.x, w.x, fmaf(c2.y, w.y, fmaf(c2.z, w.z, fmaf(c2.w, w.w, acc[32 + j]))));
            acc[48 + j] = fmaf(c3.x, w.x, fmaf(c3.y, w.y, fmaf(c3.z, w.z, fmaf(c3.w, w.w, acc[48 + j]))));
        }
        csx += c0.x + c1.x + c2.x + c3.x;
        csy += c0.y + c1.y + c2.y + c3.y;
        csz += c0.z + c1.z + c2.z + c3.z;
        csw += c0.w + c1.w + c2.w + c3.w;
        // local scan: 4 rows, fp32 accum, fp16 store (8B/lane coalesced)
        {
            _Float16* sp = Sp + (size_t)(g * 4) * COLS;
            h4 o;
            rx = fmaf(c0.x, INV_K, rx); ry = fmaf(c0.y, INV_K, ry);
            rz = fmaf(c0.z, INV_K, rz); rw = fmaf(c0.w, INV_K, rw);
            o.x = (_Float16)rx; o.y = (_Float16)ry; o.z = (_Float16)rz; o.w = (_Float16)rw;
            *reinterpret_cast<h4*>(sp) = o;
            rx = fmaf(c1.x, INV_K, rx); ry = fmaf(c1.y, INV_K, ry);
            rz = fmaf(c1.z, INV_K, rz); rw = fmaf(c1.w, INV_K, rw);
            o.x = (_Float16)rx; o.y = (_Float16)ry; o.z = (_Float16)rz; o.w = (_Float16)rw;
            *reinterpret_cast<h4*>(sp + COLS) = o;
            rx = fmaf(c2.x, INV_K, rx); ry = fmaf(c2.y, INV_K, ry);
            rz = fmaf(c2.z, INV_K, rz); rw = fmaf(c2.w, INV_K, rw);
            o.x = (_Float16)rx; o.y = (_Float16)ry; o.z = (_Float16)rz; o.w = (_Float16)rw;
            *reinterpret_cast<h4*>(sp + 2 * COLS) = o;
            rx = fmaf(c3.x, INV_K, rx); ry = fmaf(c3.y, INV_K, ry);
            rz = fmaf(c3.z, INV_K, rz); rw = fmaf(c3.w, INV_K, rw);
            o.x = (_Float16)rx; o.y = (_Float16)ry; o.z = (_Float16)rz; o.w = (_Float16)rw;
            *reinterpret_cast<h4*>(sp + 3 * COLS) = o;
        }
        // value-folding wave reduction: lane l ends with value (tl<<4)|j
#pragma unroll
        for (int m = 32; m >= 1; m >>= 1) {
            bool hi = (lane & m) != 0;
#pragma unroll
            for (int i = 0; i < m; ++i) {
                float send = hi ? acc[i] : acc[i + m];
                float recv = __shfl_xor(send, m, 64);
                acc[i] = (hi ? acc[i + m] : acc[i]) + recv;
            }
        }
        sdata[wave][g][lane] = acc[0];
    }

    float4 agg; agg.x = csx * INV_K; agg.y = csy * INV_K; agg.z = csz * INV_K; agg.w = csw * INV_K;
    csum4[(size_t)ch * COL4 + col4] = agg;

    __syncthreads();
#pragma unroll
    for (int i = 0; i < 2; ++i) {
        int idx = tid + i * 256;
        int g = idx >> 6, l = idx & 63;
        int tl = l >> 4, j = l & 15;
        float s = sdata[0][g][l] + sdata[1][g][l] + sdata[2][g][l] + sdata[3][g][l];
        s += bias[j];
        int t = ch * LT + g * 4 + tl;
        off[((size_t)t * B_DIM + cg) * 16 + j] = 1.f / (1.f + expf(-s));
    }
}

// ---- Kernel B: exclusive chunk-prefix of csum -> fp16 pfx (L2-resident) ----
// Redundant-read pattern (round-2 proven): thread (c, col4) sums csum over
// chunks < c. ~67MB of L2 reads, fully parallel, no dependencies.
__global__ void pfx_kernel(const float4* __restrict__ csum4, _Float16* __restrict__ pfxh) {
    int gid = blockIdx.x * 256 + threadIdx.x;   // NCH * COL4 threads
    int c = gid >> 11;                          // uniform within block
    int col4 = gid & (COL4 - 1);
    float rx = 0.f, ry = 0.f, rz = 0.f, rw = 0.f;
    for (int k = 0; k < c; ++k) {
        float4 v = csum4[(size_t)k * COL4 + col4];
        rx += v.x; ry += v.y; rz += v.z; rw += v.w;
    }
    h4 o; o.x = (_Float16)rx; o.y = (_Float16)ry; o.z = (_Float16)rz; o.w = (_Float16)rw;
    *reinterpret_cast<h4*>(pfxh + (size_t)c * COLS + col4 * 4) = o;
}

// ---- Kernel C: gather. S(i) = Sloc[i] + pfx[i>>5]; interp; diff. ----
__global__ void gather_kernel(const _Float16* __restrict__ Sloc,
                              const _Float16* __restrict__ pfxh,
                              const float* __restrict__ off,
                              float* __restrict__ out) {
    int bid = blockIdx.x;
    int sbid = (bid & 7) * 1024 + (bid >> 3);   // 8192 % 8 == 0 -> bijective
    int vid = sbid * 256 + threadIdx.x;         // T*B*C/8 vec elements
    int r8 = (vid & 15) << 3;
    int bh = (vid >> 4) & 63;
    int t = vid >> 10;
    int b = bh >> 3, h = bh & 7;
    const float* o = off + ((size_t)t * B_DIM + b) * 16;
    float aL = o[h], aR = o[8 + h];
    float tf = (float)t;
    float lenL = 1.f + aL * fmaxf(tf - 1.f, 0.f);
    float lenR = 1.f + aR * fmaxf((float)(T_DIM - 1) - tf - 1.f, 0.f);
    float fL = fmaxf(tf - lenL - 1.f, -1.f);
    float fR = fminf(tf + lenR, (float)(T_DIM - 1));
    int col = (bh << 7) | r8;

    float ffL = floorf(fL); int i0L = (int)ffL; float frL = fL - ffL;
    float ffR = floorf(fR); int i0R = (int)ffR; float frR = fR - ffR;
    int i0Lc = min(max(i0L, 0), T_DIM - 1), i1Lc = min(i0L + 1, T_DIM - 1);
    int i0Rc = min(max(i0R, 0), T_DIM - 1), i1Rc = min(i0R + 1, T_DIM - 1);

    const h8 zero8 = {0, 0, 0, 0, 0, 0, 0, 0};
    // row value = Sloc + chunk prefix (both fp16 streams, summed in fp32)
    h8 s1L = *reinterpret_cast<const h8*>(Sloc + (size_t)i1Lc * COLS + col);
    h8 p1L = *reinterpret_cast<const h8*>(pfxh + (size_t)(i1Lc >> 5) * COLS + col);
    h8 s1R = *reinterpret_cast<const h8*>(Sloc + (size_t)i1Rc * COLS + col);
    h8 p1R = *reinterpret_cast<const h8*>(pfxh + (size_t)(i1Rc >> 5) * COLS + col);
    h8 s0L = zero8, p0L = zero8, s0R = zero8, p0R = zero8;
    if (i0L >= 0) {
        s0L = *reinterpret_cast<const h8*>(Sloc + (size_t)i0Lc * COLS + col);
        p0L = *reinterpret_cast<const h8*>(pfxh + (size_t)(i0Lc >> 5) * COLS + col);
    }
    if (i0R >= 0) {
        s0R = *reinterpret_cast<const h8*>(Sloc + (size_t)i0Rc * COLS + col);
        p0R = *reinterpret_cast<const h8*>(pfxh + (size_t)(i0Rc >> 5) * COLS + col);
    }

    float res[8];
#pragma unroll
    for (int i = 0; i < 8; ++i) {
        float a0 = (float)s0R[i] + (float)p0R[i];
        float a1 = (float)s1R[i] + (float)p1R[i];
        float b0 = (float)s0L[i] + (float)p0L[i];
        float b1 = (float)s1L[i] + (float)p1L[i];
        res[i] = fmaf(frR, a1 - a0, a0) - fmaf(frL, b1 - b0, b0);
    }
    float* op = out + (size_t)vid * 8;
    *reinterpret_cast<float4*>(op)     = make_float4(res[0], res[1], res[2], res[3]);
    *reinterpret_cast<float4*>(op + 4) = make_float4(res[4], res[5], res[6], res[7]);
}

extern "C" void kernel_launch(void* const* d_in, const int* in_sizes, int n_in,
                              void* d_out, int out_size, void* d_ws, size_t ws_size,
                              hipStream_t stream) {
    const float4* x4 = (const float4*)d_in[0];
    const float* W  = (const float*)d_in[1];
    const float* bi = (const float*)d_in[2];

    char* ws = (char*)d_ws;
    const size_t S_bytes    = (size_t)T_DIM * COLS * sizeof(_Float16);    // 32 MB
    const size_t off_bytes  = (size_t)T_DIM * B_DIM * 16 * sizeof(float); // 1 MB
    const size_t csum_bytes = (size_t)NCH * COL4 * sizeof(float4);        // 2 MB
    _Float16* Sloc = (_Float16*)ws;
    float* off     = (float*)(ws + S_bytes);
    float* csum    = (float*)(ws + S_bytes + off_bytes);
    _Float16* pfxh = (_Float16*)(ws + S_bytes + off_bytes + csum_bytes);  // 1 MB

    offcsum_kernel<<<512, 256, 0, stream>>>(x4, W, bi, off, (float4*)csum, Sloc);
    pfx_kernel<<<(NCH * COL4) / 256, 256, 0, stream>>>((const float4*)csum, pfxh);
    gather_kernel<<<(T_DIM * B_DIM * C_DIM / 8) / 256, 256, 0, stream>>>(
        Sloc, pfxh, off, (float*)d_out);
}

// Round 10
// 74.943 us; speedup vs baseline: 3.9419x; 1.0243x over previous
//
#include <hip/hip_runtime.h>
#include <cmath>

#define T_DIM 2048
#define B_DIM 8
#define C_DIM 1024
#define H_DIM 8
#define R_DIM 128
#define BH_DIM 64          // B*H
#define COLS 8192          // BH*R
#define COL4 2048          // COLS/4
#define NCH 64             // scan chunks
#define LT 32              // T per chunk
__device__ __constant__ float INV_K = 0.33333333333333333f;

typedef _Float16 h4 __attribute__((ext_vector_type(4)));
typedef _Float16 h8 __attribute__((ext_vector_type(8)));

// ---- Kernel A: offsets GEMM + chunk sums + LOCAL scan (ONE x read) ----
// Round-9 body + next-group register prefetch (xn0..xn3 scalars only; no
// register arrays -> no rule-#20 scratch spill). The g+1 loads issue before
// the ~1100 cycles of FMA+fold+store work of group g, hiding HBM latency
// at the kernel's low (2 blocks/CU) occupancy.
__global__ __launch_bounds__(256, 2) void offcsum_kernel(
        const float4* __restrict__ x4, const float* __restrict__ W,
        const float* __restrict__ bias, float* __restrict__ off,
        float4* __restrict__ csum4, _Float16* __restrict__ Sloc) {
    __shared__ float Wt[16 * 1024];          // 64 KB
    __shared__ float sdata[4][8][64];        // 8 KB
    const int bid = blockIdx.x;
    const int cg = bid >> 6;                 // 0..7  == batch index b
    const int ch = bid & 63;                 // 0..63 == t chunk
    const int tid = threadIdx.x;
    const int wave = tid >> 6, lane = tid & 63;
    const int col4 = cg * 256 + tid;         // global col4 in [0, 2048)

    const float4* xp = x4 + (size_t)(ch * LT) * COL4 + col4;
    // first group's loads issued before LDS staging so they overlap it
    float4 xn0 = xp[0];
    float4 xn1 = xp[(size_t)1 * COL4];
    float4 xn2 = xp[(size_t)2 * COL4];
    float4 xn3 = xp[(size_t)3 * COL4];

    for (int idx = tid; idx < 4096; idx += 256) {
        int c = idx >> 2, j4 = (idx & 3) * 4;
        float4 w = *reinterpret_cast<const float4*>(W + c * 16 + j4);
        Wt[(j4 + 0) * 1024 + c] = w.x;
        Wt[(j4 + 1) * 1024 + c] = w.y;
        Wt[(j4 + 2) * 1024 + c] = w.z;
        Wt[(j4 + 3) * 1024 + c] = w.w;
    }
    __syncthreads();

    _Float16* Sp = Sloc + (size_t)(ch * LT) * COLS + col4 * 4;
    const int cbase = tid * 4;
    float csx = 0.f, csy = 0.f, csz = 0.f, csw = 0.f;   // chunk sum
    float rx = 0.f, ry = 0.f, rz = 0.f, rw = 0.f;       // local running scan

#pragma unroll 1
    for (int g = 0; g < 8; ++g) {
        float4 c0 = xn0, c1 = xn1, c2 = xn2, c3 = xn3;
        if (g < 7) {                          // prefetch next group
            const float4* np = xp + (size_t)((g + 1) * 4) * COL4;
            xn0 = np[0];
            xn1 = np[(size_t)1 * COL4];
            xn2 = np[(size_t)2 * COL4];
            xn3 = np[(size_t)3 * COL4];
        }
        float acc[64];
#pragma unroll
        for (int i = 0; i < 64; ++i) acc[i] = 0.f;
#pragma unroll
        for (int j = 0; j < 16; ++j) {
            float4 w = *reinterpret_cast<const float4*>(&Wt[j * 1024 + cbase]);
            acc[j]      = fmaf(c0.x, w.x, fmaf(c0.y, w.y, fmaf(c0.z, w.z, fmaf(c0.w, w.w, acc[j]))));
            acc[16 + j] = fmaf(c1.x, w.x, fmaf(c1.y, w.y, fmaf(c1.z, w.z, fmaf(c1.w, w.w, acc[16 + j]))));
            acc[32 + j] = fmaf(c2.x, w.x, fmaf(c2.y, w.y, fmaf(c2.z, w.z, fmaf(c2.w, w.w, acc[32 + j]))));
            acc[48 + j] = fmaf(c3.x, w.x, fmaf(c3.y, w.y, fmaf(c3.z, w.z, fmaf(c3.w, w.w, acc[48 + j]))));
        }
        csx += c0.x + c1.x + c2.x + c3.x;
        csy += c0.y + c1.y + c2.y + c3.y;
        csz += c0.z + c1.z + c2.z + c3.z;
        csw += c0.w + c1.w + c2.w + c3.w;
        // local scan: 4 rows, fp32 accum, fp16 store (8B/lane coalesced)
        {
            _Float16* sp = Sp + (size_t)(g * 4) * COLS;
            h4 o;
            rx = fmaf(c0.x, INV_K, rx); ry = fmaf(c0.y, INV_K, ry);
            rz = fmaf(c0.z, INV_K, rz); rw = fmaf(c0.w, INV_K, rw);
            o.x = (_Float16)rx; o.y = (_Float16)ry; o.z = (_Float16)rz; o.w = (_Float16)rw;
            *reinterpret_cast<h4*>(sp) = o;
            rx = fmaf(c1.x, INV_K, rx); ry = fmaf(c1.y, INV_K, ry);
            rz = fmaf(c1.z, INV_K, rz); rw = fmaf(c1.w, INV_K, rw);
            o.x = (_Float16)rx; o.y = (_Float16)ry; o.z = (_Float16)rz; o.w = (_Float16)rw;
            *reinterpret_cast<h4*>(sp + COLS) = o;
            rx = fmaf(c2.x, INV_K, rx); ry = fmaf(c2.y, INV_K, ry);
            rz = fmaf(c2.z, INV_K, rz); rw = fmaf(c2.w, INV_K, rw);
            o.x = (_Float16)rx; o.y = (_Float16)ry; o.z = (_Float16)rz; o.w = (_Float16)rw;
            *reinterpret_cast<h4*>(sp + 2 * COLS) = o;
            rx = fmaf(c3.x, INV_K, rx); ry = fmaf(c3.y, INV_K, ry);
            rz = fmaf(c3.z, INV_K, rz); rw = fmaf(c3.w, INV_K, rw);
            o.x = (_Float16)rx; o.y = (_Float16)ry; o.z = (_Float16)rz; o.w = (_Float16)rw;
            *reinterpret_cast<h4*>(sp + 3 * COLS) = o;
        }
        // value-folding wave reduction: lane l ends with value (tl<<4)|j
#pragma unroll
        for (int m = 32; m >= 1; m >>= 1) {
            bool hi = (lane & m) != 0;
#pragma unroll
            for (int i = 0; i < m; ++i) {
                float send = hi ? acc[i] : acc[i + m];
                float recv = __shfl_xor(send, m, 64);
                acc[i] = (hi ? acc[i + m] : acc[i]) + recv;
            }
        }
        sdata[wave][g][lane] = acc[0];
    }

    float4 agg; agg.x = csx * INV_K; agg.y = csy * INV_K; agg.z = csz * INV_K; agg.w = csw * INV_K;
    csum4[(size_t)ch * COL4 + col4] = agg;

    __syncthreads();
#pragma unroll
    for (int i = 0; i < 2; ++i) {
        int idx = tid + i * 256;
        int g = idx >> 6, l = idx & 63;
        int tl = l >> 4, j = l & 15;
        float s = sdata[0][g][l] + sdata[1][g][l] + sdata[2][g][l] + sdata[3][g][l];
        s += bias[j];
        int t = ch * LT + g * 4 + tl;
        off[((size_t)t * B_DIM + cg) * 16 + j] = 1.f / (1.f + expf(-s));
    }
}

// ---- Kernel B: exclusive chunk-prefix of csum -> fp16 pfx (L2-resident) ----
__global__ void pfx_kernel(const float4* __restrict__ csum4, _Float16* __restrict__ pfxh) {
    int gid = blockIdx.x * 256 + threadIdx.x;   // NCH * COL4 threads
    int c = gid >> 11;                          // uniform within block
    int col4 = gid & (COL4 - 1);
    float rx = 0.f, ry = 0.f, rz = 0.f, rw = 0.f;
    for (int k = 0; k < c; ++k) {
        float4 v = csum4[(size_t)k * COL4 + col4];
        rx += v.x; ry += v.y; rz += v.z; rw += v.w;
    }
    h4 o; o.x = (_Float16)rx; o.y = (_Float16)ry; o.z = (_Float16)rz; o.w = (_Float16)rw;
    *reinterpret_cast<h4*>(pfxh + (size_t)c * COLS + col4 * 4) = o;
}

// ---- Kernel C: gather. S(i) = Sloc[i] + pfx[i>>5]; interp; diff. ----
__global__ void gather_kernel(const _Float16* __restrict__ Sloc,
                              const _Float16* __restrict__ pfxh,
                              const float* __restrict__ off,
                              float* __restrict__ out) {
    int bid = blockIdx.x;
    int sbid = (bid & 7) * 1024 + (bid >> 3);   // 8192 % 8 == 0 -> bijective
    int vid = sbid * 256 + threadIdx.x;         // T*B*C/8 vec elements
    int r8 = (vid & 15) << 3;
    int bh = (vid >> 4) & 63;
    int t = vid >> 10;
    int b = bh >> 3, h = bh & 7;
    const float* o = off + ((size_t)t * B_DIM + b) * 16;
    float aL = o[h], aR = o[8 + h];
    float tf = (float)t;
    float lenL = 1.f + aL * fmaxf(tf - 1.f, 0.f);
    float lenR = 1.f + aR * fmaxf((float)(T_DIM - 1) - tf - 1.f, 0.f);
    float fL = fmaxf(tf - lenL - 1.f, -1.f);
    float fR = fminf(tf + lenR, (float)(T_DIM - 1));
    int col = (bh << 7) | r8;

    float ffL = floorf(fL); int i0L = (int)ffL; float frL = fL - ffL;
    float ffR = floorf(fR); int i0R = (int)ffR; float frR = fR - ffR;
    int i0Lc = min(max(i0L, 0), T_DIM - 1), i1Lc = min(i0L + 1, T_DIM - 1);
    int i0Rc = min(max(i0R, 0), T_DIM - 1), i1Rc = min(i0R + 1, T_DIM - 1);

    const h8 zero8 = {0, 0, 0, 0, 0, 0, 0, 0};
    // row value = Sloc + chunk prefix (both fp16 streams, summed in fp32)
    h8 s1L = *reinterpret_cast<const h8*>(Sloc + (size_t)i1Lc * COLS + col);
    h8 p1L = *reinterpret_cast<const h8*>(pfxh + (size_t)(i1Lc >> 5) * COLS + col);
    h8 s1R = *reinterpret_cast<const h8*>(Sloc + (size_t)i1Rc * COLS + col);
    h8 p1R = *reinterpret_cast<const h8*>(pfxh + (size_t)(i1Rc >> 5) * COLS + col);
    h8 s0L = zero8, p0L = zero8, s0R = zero8, p0R = zero8;
    if (i0L >= 0) {
        s0L = *reinterpret_cast<const h8*>(Sloc + (size_t)i0Lc * COLS + col);
        p0L = *reinterpret_cast<const h8*>(pfxh + (size_t)(i0Lc >> 5) * COLS + col);
    }
    if (i0R >= 0) {
        s0R = *reinterpret_cast<const h8*>(Sloc + (size_t)i0Rc * COLS + col);
        p0R = *reinterpret_cast<const h8*>(pfxh + (size_t)(i0Rc >> 5) * COLS + col);
    }

    float res[8];
#pragma unroll
    for (int i = 0; i < 8; ++i) {
        float a0 = (float)s0R[i] + (float)p0R[i];
        float a1 = (float)s1R[i] + (float)p1R[i];
        float b0 = (float)s0L[i] + (float)p0L[i];
        float b1 = (float)s1L[i] + (float)p1L[i];
        res[i] = fmaf(frR, a1 - a0, a0) - fmaf(frL, b1 - b0, b0);
    }
    float* op = out + (size_t)vid * 8;
    *reinterpret_cast<float4*>(op)     = make_float4(res[0], res[1], res[2], res[3]);
    *reinterpret_cast<float4*>(op + 4) = make_float4(res[4], res[5], res[6], res[7]);
}

extern "C" void kernel_launch(void* const* d_in, const int* in_sizes, int n_in,
                              void* d_out, int out_size, void* d_ws, size_t ws_size,
                              hipStream_t stream) {
    const float4* x4 = (const float4*)d_in[0];
    const float* W  = (const float*)d_in[1];
    const float* bi = (const float*)d_in[2];

    char* ws = (char*)d_ws;
    const size_t S_bytes    = (size_t)T_DIM * COLS * sizeof(_Float16);    // 32 MB
    const size_t off_bytes  = (size_t)T_DIM * B_DIM * 16 * sizeof(float); // 1 MB
    const size_t csum_bytes = (size_t)NCH * COL4 * sizeof(float4);        // 2 MB
    _Float16* Sloc = (_Float16*)ws;
    float* off     = (float*)(ws + S_bytes);
    float* csum    = (float*)(ws + S_bytes + off_bytes);
    _Float16* pfxh = (_Float16*)(ws + S_bytes + off_bytes + csum_bytes);  // 1 MB

    offcsum_kernel<<<512, 256, 0, stream>>>(x4, W, bi, off, (float4*)csum, Sloc);
    pfx_kernel<<<(NCH * COL4) / 256, 256, 0, stream>>>((const float4*)csum, pfxh);
    gather_kernel<<<(T_DIM * B_DIM * C_DIM / 8) / 256, 256, 0, stream>>>(
        Sloc, pfxh, off, (float*)d_out);
}